// Round 1
// baseline (1047.882 us; speedup 1.0000x reference)
//
#include <hip/hip_runtime.h>
#include <cstdint>
#include <cstddef>

#define EPS 1e-5f

__device__ __forceinline__ float4 ld4(const float* p) { return *(const float4*)p; }
__device__ __forceinline__ void st4(float* p, float4 v) { *(float4*)p = v; }

// ---------------------------------------------------------------------------
// Generic tiled fp32 GEMM: out[M=4096, N] = A[M,K] @ W[K,N] (+bias) (+relu)
// A can be a concat of A1 (row len K1) and A2 (row len K-K1).
// grid = (64, N/64), block = 256, micro-tile 4x4, BK=32.
// ---------------------------------------------------------------------------
template<bool RELU>
__launch_bounds__(256)
__global__ void gemm_bias_kernel(const float* __restrict__ A1,
                                 const float* __restrict__ A2, int K1,
                                 const float* __restrict__ W,
                                 const float* __restrict__ bias,
                                 float* __restrict__ out,
                                 int N, int K) {
    __shared__ float As[32 * 68];
    __shared__ float Bs[32 * 68];
    const int tid = threadIdx.x;
    const int bx = blockIdx.x, by = blockIdx.y;
    const int tx = tid & 15, ty = tid >> 4;

    float acc[4][4];
#pragma unroll
    for (int a = 0; a < 4; ++a)
#pragma unroll
        for (int b = 0; b < 4; ++b) acc[a][b] = 0.f;

    for (int k0 = 0; k0 < K; k0 += 32) {
        __syncthreads();
#pragma unroll
        for (int itr = 0; itr < 2; ++itr) {
            int idx = tid + itr * 256;
            // stage A (transposed): 64 rows x 32 k
            int r = idx >> 3, c4 = idx & 7;
            int kk = k0 + c4 * 4;
            const float* src; int rl, kl;
            if (kk < K1) { src = A1; rl = K1; kl = kk; }
            else         { src = A2; rl = K - K1; kl = kk - K1; }
            float4 a = ld4(&src[(size_t)(bx * 64 + r) * rl + kl]);
            As[(c4 * 4 + 0) * 68 + r] = a.x;
            As[(c4 * 4 + 1) * 68 + r] = a.y;
            As[(c4 * 4 + 2) * 68 + r] = a.z;
            As[(c4 * 4 + 3) * 68 + r] = a.w;
            // stage B: 32 k x 64 n
            int kb = idx >> 4, n4 = (idx & 15) * 4;
            float4 bvv = ld4(&W[(size_t)(k0 + kb) * N + by * 64 + n4]);
            st4(&Bs[kb * 68 + n4], bvv);
        }
        __syncthreads();
#pragma unroll
        for (int kk2 = 0; kk2 < 32; ++kk2) {
            float4 av = ld4(&As[kk2 * 68 + ty * 4]);
            float4 bv = ld4(&Bs[kk2 * 68 + tx * 4]);
            acc[0][0] = fmaf(av.x, bv.x, acc[0][0]);
            acc[0][1] = fmaf(av.x, bv.y, acc[0][1]);
            acc[0][2] = fmaf(av.x, bv.z, acc[0][2]);
            acc[0][3] = fmaf(av.x, bv.w, acc[0][3]);
            acc[1][0] = fmaf(av.y, bv.x, acc[1][0]);
            acc[1][1] = fmaf(av.y, bv.y, acc[1][1]);
            acc[1][2] = fmaf(av.y, bv.z, acc[1][2]);
            acc[1][3] = fmaf(av.y, bv.w, acc[1][3]);
            acc[2][0] = fmaf(av.z, bv.x, acc[2][0]);
            acc[2][1] = fmaf(av.z, bv.y, acc[2][1]);
            acc[2][2] = fmaf(av.z, bv.z, acc[2][2]);
            acc[2][3] = fmaf(av.z, bv.w, acc[2][3]);
            acc[3][0] = fmaf(av.w, bv.x, acc[3][0]);
            acc[3][1] = fmaf(av.w, bv.y, acc[3][1]);
            acc[3][2] = fmaf(av.w, bv.z, acc[3][2]);
            acc[3][3] = fmaf(av.w, bv.w, acc[3][3]);
        }
    }
    float4 bb = {0.f, 0.f, 0.f, 0.f};
    if (bias) bb = ld4(&bias[by * 64 + tx * 4]);
#pragma unroll
    for (int mi = 0; mi < 4; ++mi) {
        float4 y;
        y.x = acc[mi][0] + bb.x;
        y.y = acc[mi][1] + bb.y;
        y.z = acc[mi][2] + bb.z;
        y.w = acc[mi][3] + bb.w;
        if (RELU) {
            y.x = fmaxf(y.x, 0.f); y.y = fmaxf(y.y, 0.f);
            y.z = fmaxf(y.z, 0.f); y.w = fmaxf(y.w, 0.f);
        }
        st4(&out[(size_t)(bx * 64 + ty * 4 + mi) * N + by * 64 + tx * 4], y);
    }
}

// ---------------------------------------------------------------------------
// Fused attention: per block = (batch b, 8 query rows). Streams p once,
// computes qk + pbias, no-max softmax (scores bounded ~|1|), PV accumulate.
// q,k,v layout: (L*B, 384) rows, row = l*8 + b, col = h*32 + d.
// grid = (64, 8), block = 256.
// ---------------------------------------------------------------------------
__launch_bounds__(256)
__global__ void attn_kernel(const float* __restrict__ q,
                            const float* __restrict__ k,
                            const float* __restrict__ v,
                            const float* __restrict__ p,
                            const float* __restrict__ w2d,
                            const float* __restrict__ b2d,
                            float* __restrict__ o) {
    __shared__ float q_s[8 * 388];
    __shared__ float k_s[16 * 388];
    __shared__ float v_s[16 * 388];
    __shared__ float e_s[128 * 13];
    __shared__ float l_s[8][12];

    const int tid = threadIdx.x;
    const int it = blockIdx.x;   // query tile 0..63
    const int b  = blockIdx.y;   // batch 0..7
    const int i0 = it * 8;
    const float scale = 0.05103103630798288f;  // 1/sqrt(384)

    // load + scale q tile (8 rows x 384)
    for (int idx = tid; idx < 8 * 96; idx += 256) {
        int r = idx / 96, c4 = (idx % 96) * 4;
        float4 t = ld4(&q[(size_t)((i0 + r) * 8 + b) * 384 + c4]);
        t.x *= scale; t.y *= scale; t.z *= scale; t.w *= scale;
        st4(&q_s[r * 388 + c4], t);
    }

    // wave-uniform half split (bit7) so W2d loads scalarize
    const int half = __builtin_amdgcn_readfirstlane((int)(tid >> 7));
    const int pair = tid & 127;           // (i,j) pair within tile
    const int pi = pair >> 4, pj = pair & 15;
    const int e0 = half * 32;             // pbias e-range
    const int d0 = half * 16;             // qk d-range
    const int i_b = tid >> 5, l32 = tid & 31;  // phase-B mapping
    const float* w2dh = w2d + e0 * 12;

    float l_part[12];
#pragma unroll
    for (int h = 0; h < 12; ++h) l_part[h] = 0.f;
    float4 oacc[3];
#pragma unroll
    for (int c = 0; c < 3; ++c) { oacc[c].x = 0.f; oacc[c].y = 0.f; oacc[c].z = 0.f; oacc[c].w = 0.f; }

    for (int t = 0; t < 32; ++t) {
        const int j0 = t * 16;
        __syncthreads();
        // stage k,v tiles (16 rows x 384 each)
        for (int idx = tid; idx < 16 * 96; idx += 256) {
            int r = idx / 96, c4 = (idx % 96) * 4;
            size_t grow = (size_t)((j0 + r) * 8 + b) * 384 + c4;
            st4(&k_s[r * 388 + c4], ld4(&k[grow]));
            st4(&v_s[r * 388 + c4], ld4(&v[grow]));
        }
        __syncthreads();

        // ---- phase A: partial scores (each wave does one e/d half) ----
        const float* pp = p + (((size_t)b * 512 + (i0 + pi)) * 512 + (j0 + pj)) * 64 + e0;
        float4 pr[8];
#pragma unroll
        for (int c = 0; c < 8; ++c) pr[c] = ld4(pp + c * 4);
        float S[12];
#pragma unroll
        for (int h = 0; h < 12; ++h) S[h] = (half == 0) ? b2d[h] : 0.f;
        const float* prf = (const float*)pr;
#pragma unroll
        for (int e = 0; e < 32; ++e) {
            float pe = prf[e];
#pragma unroll
            for (int h = 0; h < 12; ++h) S[h] = fmaf(pe, w2dh[e * 12 + h], S[h]);
        }
#pragma unroll
        for (int h = 0; h < 12; ++h) {
            const float4* qr4 = (const float4*)&q_s[pi * 388 + h * 32 + d0];
            const float4* kr4 = (const float4*)&k_s[pj * 388 + h * 32 + d0];
            float a0 = 0.f;
#pragma unroll
            for (int dd = 0; dd < 4; ++dd) {
                float4 qa = qr4[dd], ka = kr4[dd];
                a0 = fmaf(qa.x, ka.x, a0); a0 = fmaf(qa.y, ka.y, a0);
                a0 = fmaf(qa.z, ka.z, a0); a0 = fmaf(qa.w, ka.w, a0);
            }
            S[h] += a0;
        }
        if (half == 0) {
#pragma unroll
            for (int h = 0; h < 12; ++h) e_s[pair * 13 + h] = S[h];
        }
        __syncthreads();
        if (half == 1) {
#pragma unroll
            for (int h = 0; h < 12; ++h) {
                float E = __expf(S[h] + e_s[pair * 13 + h]);
                e_s[pair * 13 + h] = E;
                l_part[h] += E;
            }
        }
        __syncthreads();

        // ---- phase B: PV accumulate ----
#pragma unroll
        for (int j = 0; j < 16; ++j) {
            const float* er = &e_s[(i_b * 16 + j) * 13];
#pragma unroll
            for (int c = 0; c < 3; ++c) {
                float prob = er[c * 4 + (l32 >> 3)];
                float4 v4 = ld4(&v_s[j * 388 + c * 128 + l32 * 4]);
                oacc[c].x = fmaf(prob, v4.x, oacc[c].x);
                oacc[c].y = fmaf(prob, v4.y, oacc[c].y);
                oacc[c].z = fmaf(prob, v4.z, oacc[c].z);
                oacc[c].w = fmaf(prob, v4.w, oacc[c].w);
            }
        }
    }

    // ---- final softmax denominator reduce ----
    if (half == 1) {
#pragma unroll
        for (int h = 0; h < 12; ++h) {
            float s0 = l_part[h];
            s0 += __shfl_xor(s0, 1);
            s0 += __shfl_xor(s0, 2);
            s0 += __shfl_xor(s0, 4);
            s0 += __shfl_xor(s0, 8);
            l_part[h] = s0;
        }
        int lane = tid & 63;
        int il = lane >> 4;
        int hh = lane & 15;
        int grp = (tid >> 6) & 1;      // wave2 -> i 0..3, wave3 -> i 4..7
        int ig = grp * 4 + il;
#pragma unroll
        for (int h = 0; h < 12; ++h)
            if (hh == h) l_s[ig][h] = l_part[h];
    }
    __syncthreads();
#pragma unroll
    for (int c = 0; c < 3; ++c) {
        float inv = 1.0f / l_s[i_b][c * 4 + (l32 >> 3)];
        float4 y;
        y.x = oacc[c].x * inv; y.y = oacc[c].y * inv;
        y.z = oacc[c].z * inv; y.w = oacc[c].w * inv;
        st4(&o[(size_t)((i0 + i_b) * 8 + b) * 384 + c * 128 + l32 * 4], y);
    }
}

// ---------------------------------------------------------------------------
// Residual add + LayerNorm over 128 cols. 2 rows per block of 256.
// ---------------------------------------------------------------------------
__launch_bounds__(256)
__global__ void ln_kernel(const float* __restrict__ resid,
                          const float* __restrict__ y,
                          const float* __restrict__ g,
                          const float* __restrict__ be,
                          float* __restrict__ out) {
    const int tid = threadIdx.x;
    const int row = blockIdx.x * 2 + (tid >> 7);
    const int c = tid & 127;
    __shared__ float red[4][2];
    size_t idx = (size_t)row * 128 + c;
    float val = resid[idx] + y[idx];
    float s0 = val, sq = val * val;
#pragma unroll
    for (int m = 1; m <= 32; m <<= 1) {
        s0 += __shfl_xor(s0, m);
        sq += __shfl_xor(sq, m);
    }
    const int w = tid >> 6;
    if ((tid & 63) == 0) { red[w][0] = s0; red[w][1] = sq; }
    __syncthreads();
    float S  = red[w][0] + red[w ^ 1][0];
    float SQ = red[w][1] + red[w ^ 1][1];
    float mean = S * (1.f / 128.f);
    float var  = SQ * (1.f / 128.f) - mean * mean;
    out[idx] = (val - mean) * rsqrtf(var + EPS) * g[c] + be[c];
}

// ---------------------------------------------------------------------------
extern "C" void kernel_launch(void* const* d_in, const int* in_sizes, int n_in,
                              void* d_out, int out_size, void* d_ws, size_t ws_size,
                              hipStream_t stream) {
    const float* s   = (const float*)d_in[0];
    const float* x   = (const float*)d_in[1];
    const float* p   = (const float*)d_in[2];
    const float* Wq  = (const float*)d_in[3];
    const float* Wk  = (const float*)d_in[4];
    const float* Wv  = (const float*)d_in[5];
    const float* Wo  = (const float*)d_in[6];
    const float* bo  = (const float*)d_in[7];
    const float* W2d = (const float*)d_in[8];
    const float* b2d = (const float*)d_in[9];
    const float* W1  = (const float*)d_in[10];
    const float* b1  = (const float*)d_in[11];
    const float* W2  = (const float*)d_in[12];
    const float* b2  = (const float*)d_in[13];
    const float* g1  = (const float*)d_in[14];
    const float* be1 = (const float*)d_in[15];
    const float* g2  = (const float*)d_in[16];
    const float* be2 = (const float*)d_in[17];
    float* out = (float*)d_out;

    float* ws   = (float*)d_ws;
    float* q_ws = ws;                       // 4096*384
    float* k_ws = q_ws + 4096 * 384;
    float* v_ws = k_ws + 4096 * 384;
    float* o_ws = v_ws + 4096 * 384;
    float* t1   = o_ws + 4096 * 384;        // 4096*128
    float* s1   = t1 + 4096 * 128;          // 4096*128
    float* h_ws = s1 + 4096 * 128;          // 4096*512
    float* t2   = h_ws + 4096 * 512;        // 4096*128

    dim3 blk(256);
    // QKV projections (no bias in reference)
    gemm_bias_kernel<false><<<dim3(64, 6), blk, 0, stream>>>(s, nullptr, 128, Wq, nullptr, q_ws, 384, 128);
    gemm_bias_kernel<false><<<dim3(64, 6), blk, 0, stream>>>(s, nullptr, 128, Wk, nullptr, k_ws, 384, 128);
    gemm_bias_kernel<false><<<dim3(64, 6), blk, 0, stream>>>(s, nullptr, 128, Wv, nullptr, v_ws, 384, 128);
    // fused attention with pair bias
    attn_kernel<<<dim3(64, 8), blk, 0, stream>>>(q_ws, k_ws, v_ws, p, W2d, b2d, o_ws);
    // output projection + bias
    gemm_bias_kernel<false><<<dim3(64, 2), blk, 0, stream>>>(o_ws, nullptr, 384, Wo, bo, t1, 128, 384);
    // residual + LN1
    ln_kernel<<<dim3(2048), blk, 0, stream>>>(s, t1, g1, be1, s1);
    // FFN: relu([s1,x] @ W1 + b1)
    gemm_bias_kernel<true ><<<dim3(64, 8), blk, 0, stream>>>(s1, x, 128, W1, b1, h_ws, 512, 192);
    // FFN second matmul
    gemm_bias_kernel<false><<<dim3(64, 2), blk, 0, stream>>>(h_ws, nullptr, 512, W2, b2, t2, 128, 512);
    // residual + LN2 -> output
    ln_kernel<<<dim3(2048), blk, 0, stream>>>(s1, t2, g2, be2, out);
}